// Round 1
// baseline (382.471 us; speedup 1.0000x reference)
//
#include <hip/hip_runtime.h>
#include <stdint.h>
#include <math.h>

#define NCLS 81
#define NFG  80
#define NPI  1024
#define NIMG 8
#define DETS 100
#define SCORE_T 0.05f
#define NMS_T   0.5f

static constexpr float BBOX_CLIP = 4.1351665567423557f; // log(1000/16)

// ---------------- Kernel 1: per-row softmax stats ----------------
__global__ __launch_bounds__(256) void softmax_stats(
    const float* __restrict__ logits, float* __restrict__ rowmax,
    float* __restrict__ den, int M)
{
    int m = blockIdx.x * blockDim.x + threadIdx.x;
    if (m >= M) return;
    const float* r = logits + (size_t)m * NCLS;
    float mx = r[0];
    #pragma unroll
    for (int j = 1; j < NCLS; ++j) mx = fmaxf(mx, r[j]);
    float s = 0.f;
    #pragma unroll
    for (int j = 0; j < NCLS; ++j) s += expf(r[j] - mx);
    rowmax[m] = mx;
    den[m] = s;
}

// ---------------- Kernel 2: per-(image,class) NMS ----------------
// One block per problem (640). LDS: boxes by proposal id (16KB),
// key64 sort array (8KB), keep flags (4KB).
__global__ __launch_bounds__(256) void per_class_nms(
    const float* __restrict__ logits, const float* __restrict__ boxreg,
    const float* __restrict__ props, const float* __restrict__ rowmax,
    const float* __restrict__ den, const int* __restrict__ hptr,
    const int* __restrict__ wptr, int* __restrict__ out_cnt,
    float* __restrict__ out_score, unsigned* __restrict__ out_key,
    float* __restrict__ out_box)
{
    int pid = blockIdx.x;           // 0..639
    int img = pid / NFG;
    int c   = pid % NFG;            // fg class row; label = c+1
    int cls = c + 1;

    __shared__ float box_lds[NPI][4];
    __shared__ unsigned long long key[NPI];
    __shared__ int keep[NPI];
    __shared__ int cnt;

    float W1 = (float)(*wptr - 1);
    float H1 = (float)(*hptr - 1);

    if (threadIdx.x == 0) cnt = 0;
    for (int i = threadIdx.x; i < NPI; i += blockDim.x) key[i] = 0ULL;
    __syncthreads();

    for (int m = threadIdx.x; m < NPI; m += blockDim.x) {
        int g = img * NPI + m;
        float prob = expf(logits[(size_t)g * NCLS + cls] - rowmax[g]) / den[g];
        if (prob > SCORE_T) {
            // decode (reference _decode formula order)
            float x1 = props[g * 4 + 0], y1 = props[g * 4 + 1];
            float x2 = props[g * 4 + 2], y2 = props[g * 4 + 3];
            float w  = x2 - x1 + 1.0f, h = y2 - y1 + 1.0f;
            float cx = x1 + 0.5f * w,  cy = y1 + 0.5f * h;
            const float* rc = boxreg + (size_t)g * (4 * NCLS) + 4 * cls;
            float dx = rc[0] / 10.0f, dy = rc[1] / 10.0f;
            float dw = fminf(rc[2] / 5.0f, BBOX_CLIP);
            float dh = fminf(rc[3] / 5.0f, BBOX_CLIP);
            float pcx = dx * w + cx, pcy = dy * h + cy;
            float pw = expf(dw) * w, ph = expf(dh) * h;
            float bx1 = pcx - 0.5f * pw;
            float by1 = pcy - 0.5f * ph;
            float bx2 = pcx + 0.5f * pw - 1.0f;
            float by2 = pcy + 0.5f * ph - 1.0f;
            // clip
            bx1 = fminf(fmaxf(bx1, 0.f), W1);
            bx2 = fminf(fmaxf(bx2, 0.f), W1);
            by1 = fminf(fmaxf(by1, 0.f), H1);
            by2 = fminf(fmaxf(by2, 0.f), H1);
            box_lds[m][0] = bx1; box_lds[m][1] = by1;
            box_lds[m][2] = bx2; box_lds[m][3] = by2;
            int p = atomicAdd(&cnt, 1);
            unsigned fb = __float_as_uint(prob); // prob>0 -> monotonic bits
            key[p] = ((unsigned long long)fb << 32) | (unsigned)(NPI - 1 - m);
        }
    }
    __syncthreads();
    int n = cnt;

    // bitonic sort, 1024 keys, descending (sentinel 0 sinks to end)
    for (int k = 2; k <= NPI; k <<= 1) {
        for (int j = k >> 1; j > 0; j >>= 1) {
            for (int i = threadIdx.x; i < NPI; i += blockDim.x) {
                int ixj = i ^ j;
                if (ixj > i) {
                    unsigned long long a = key[i], b = key[ixj];
                    bool up = (i & k) == 0; // descending sort
                    if (up ? (a < b) : (a > b)) { key[i] = b; key[ixj] = a; }
                }
            }
            __syncthreads();
        }
    }

    for (int i = threadIdx.x; i < NPI; i += blockDim.x) keep[i] = (i < n) ? 1 : 0;
    __syncthreads();

    // greedy NMS (reference semantics: i suppresses j>i iff keep[i] && iou>0.5)
    for (int i = 0; i < n; ++i) {
        if (keep[i]) {
            unsigned long long ki = key[i];
            int mi = NPI - 1 - (int)(ki & 0xFFFFFFFFu);
            float ax1 = box_lds[mi][0], ay1 = box_lds[mi][1];
            float ax2 = box_lds[mi][2], ay2 = box_lds[mi][3];
            float aarea = (ax2 - ax1 + 1.f) * (ay2 - ay1 + 1.f);
            for (int jj = i + 1 + (int)threadIdx.x; jj < n; jj += blockDim.x) {
                if (keep[jj]) {
                    int mj = NPI - 1 - (int)(key[jj] & 0xFFFFFFFFu);
                    float bx1 = box_lds[mj][0], by1 = box_lds[mj][1];
                    float bx2 = box_lds[mj][2], by2 = box_lds[mj][3];
                    float xx1 = fmaxf(ax1, bx1), yy1 = fmaxf(ay1, by1);
                    float xx2 = fminf(ax2, bx2), yy2 = fminf(ay2, by2);
                    float iw = fmaxf(xx2 - xx1 + 1.f, 0.f);
                    float ih = fmaxf(yy2 - yy1 + 1.f, 0.f);
                    float inter = iw * ih;
                    float barea = (bx2 - bx1 + 1.f) * (by2 - by1 + 1.f);
                    float iou = inter / (aarea + barea - inter);
                    if (iou > NMS_T) keep[jj] = 0;
                }
            }
        }
        __syncthreads();
    }

    // compact first <=100 kept entries (rank order); flatkey = c*1024 + rank
    if (threadIdx.x == 0) {
        int outn = 0;
        for (int i = 0; i < n && outn < DETS; ++i) {
            if (keep[i]) {
                unsigned long long ki = key[i];
                float sc = __uint_as_float((unsigned)(ki >> 32));
                int mi = NPI - 1 - (int)(ki & 0xFFFFFFFFu);
                int slot = pid * DETS + outn;
                out_score[slot] = sc;
                out_key[slot] = (unsigned)(c * NPI + i);
                out_box[slot * 4 + 0] = box_lds[mi][0];
                out_box[slot * 4 + 1] = box_lds[mi][1];
                out_box[slot * 4 + 2] = box_lds[mi][2];
                out_box[slot * 4 + 3] = box_lds[mi][3];
                ++outn;
            }
        }
        out_cnt[pid] = outn;
    }
}

// ---------------- Kernel 3: per-image top-100 merge ----------------
// 1 block per image. LDS keys[8000] (64KB) + reduction scratch.
__global__ __launch_bounds__(256) void topk_merge(
    const int* __restrict__ cnts, const float* __restrict__ escore,
    const unsigned* __restrict__ ekey, const float* __restrict__ ebox,
    float* __restrict__ out)
{
    int img = blockIdx.x;
    __shared__ unsigned long long keys[NFG * DETS];
    __shared__ unsigned long long red[256];
    __shared__ int redpos[256];

    for (int p = threadIdx.x; p < NFG * DETS; p += blockDim.x) {
        int cc = p / DETS, k = p % DETS;
        unsigned long long kv = 0ULL;
        if (k < cnts[img * NFG + cc]) {
            int gp = img * NFG * DETS + p;
            unsigned fb = __float_as_uint(escore[gp]);
            kv = ((unsigned long long)fb << 32) | (unsigned)(~ekey[gp]);
        }
        keys[p] = kv;
    }
    __syncthreads();

    float* oScore = out;                        // [8][100]
    float* oBox   = out + NIMG * DETS;          // [8][100][4]
    float* oLab   = out + NIMG * DETS * 5;      // [8][100]

    for (int k = 0; k < DETS; ++k) {
        unsigned long long best = 0ULL; int bpos = -1;
        for (int p = threadIdx.x; p < NFG * DETS; p += blockDim.x)
            if (keys[p] > best) { best = keys[p]; bpos = p; }
        red[threadIdx.x] = best;
        redpos[threadIdx.x] = bpos;
        __syncthreads();
        for (int s = 128; s > 0; s >>= 1) {
            if ((int)threadIdx.x < s) {
                if (red[threadIdx.x + s] > red[threadIdx.x]) {
                    red[threadIdx.x] = red[threadIdx.x + s];
                    redpos[threadIdx.x] = redpos[threadIdx.x + s];
                }
            }
            __syncthreads();
        }
        if (threadIdx.x == 0) {
            unsigned long long b = red[0];
            int p = redpos[0];
            int o = img * DETS + k;
            if (b != 0ULL) {
                float sc = __uint_as_float((unsigned)(b >> 32));
                unsigned fk = ~(unsigned)(b & 0xFFFFFFFFu); // flatkey
                int gp = img * NFG * DETS + p;
                oScore[o] = sc;
                oBox[o * 4 + 0] = ebox[gp * 4 + 0];
                oBox[o * 4 + 1] = ebox[gp * 4 + 1];
                oBox[o * 4 + 2] = ebox[gp * 4 + 2];
                oBox[o * 4 + 3] = ebox[gp * 4 + 3];
                oLab[o] = (float)((fk >> 10) + 1);
                keys[p] = 0ULL; // exclude from further selection
            } else {
                oScore[o] = 0.f;
                oBox[o * 4 + 0] = 0.f; oBox[o * 4 + 1] = 0.f;
                oBox[o * 4 + 2] = 0.f; oBox[o * 4 + 3] = 0.f;
                oLab[o] = 0.f;
            }
        }
        __syncthreads();
    }
}

extern "C" void kernel_launch(void* const* d_in, const int* in_sizes, int n_in,
                              void* d_out, int out_size, void* d_ws, size_t ws_size,
                              hipStream_t stream) {
    const float* logits = (const float*)d_in[0];
    const float* boxreg = (const float*)d_in[1];
    const float* props  = (const float*)d_in[2];
    const int*   hptr   = (const int*)d_in[3];
    const int*   wptr   = (const int*)d_in[4];
    float* out = (float*)d_out;
    int M = in_sizes[0] / NCLS; // 8192

    char* ws = (char*)d_ws;
    float*    rowmax = (float*)ws;    ws += (size_t)M * sizeof(float);
    float*    den    = (float*)ws;    ws += (size_t)M * sizeof(float);
    int*      cnt    = (int*)ws;      ws += (size_t)NIMG * NFG * sizeof(int);
    float*    escore = (float*)ws;    ws += (size_t)NIMG * NFG * DETS * sizeof(float);
    unsigned* ekey   = (unsigned*)ws; ws += (size_t)NIMG * NFG * DETS * sizeof(unsigned);
    float*    ebox   = (float*)ws;    ws += (size_t)NIMG * NFG * DETS * 4 * sizeof(float);

    softmax_stats<<<(M + 255) / 256, 256, 0, stream>>>(logits, rowmax, den, M);
    per_class_nms<<<NIMG * NFG, 256, 0, stream>>>(
        logits, boxreg, props, rowmax, den, hptr, wptr, cnt, escore, ekey, ebox);
    topk_merge<<<NIMG, 256, 0, stream>>>(cnt, escore, ekey, ebox, out);
}

// Round 2
// 184.415 us; speedup vs baseline: 2.0740x; 2.0740x over previous
//
#include <hip/hip_runtime.h>
#include <stdint.h>
#include <math.h>

#define NCLS 81
#define NFG  80
#define NPI  1024
#define NIMG 8
#define DETS 100
#define SCORE_T 0.05f
#define NMS_T   0.5f
#define MERGE_N 8192   // next pow2 >= NFG*DETS (8000)

static constexpr float BBOX_CLIP = 4.1351665567423557f; // log(1000/16)

// ---------------- Kernel 1: per-row softmax stats ----------------
__global__ __launch_bounds__(256) void softmax_stats(
    const float* __restrict__ logits, float* __restrict__ rowmax,
    float* __restrict__ den, int M)
{
    int m = blockIdx.x * blockDim.x + threadIdx.x;
    if (m >= M) return;
    const float* r = logits + (size_t)m * NCLS;
    float mx = r[0];
    #pragma unroll
    for (int j = 1; j < NCLS; ++j) mx = fmaxf(mx, r[j]);
    float s = 0.f;
    #pragma unroll
    for (int j = 0; j < NCLS; ++j) s += expf(r[j] - mx);
    rowmax[m] = mx;
    den[m] = s;
}

// ---------------- Kernel 2: per-(image,class) NMS ----------------
__global__ __launch_bounds__(256) void per_class_nms(
    const float* __restrict__ logits, const float* __restrict__ boxreg,
    const float* __restrict__ props, const float* __restrict__ rowmax,
    const float* __restrict__ den, const int* __restrict__ hptr,
    const int* __restrict__ wptr, int* __restrict__ out_cnt,
    float* __restrict__ out_score, unsigned* __restrict__ out_key,
    float* __restrict__ out_box)
{
    int pid = blockIdx.x;           // 0..639
    int img = pid / NFG;
    int c   = pid % NFG;            // fg class row; label = c+1
    int cls = c + 1;

    __shared__ float box_lds[NPI][4];
    __shared__ unsigned long long key[NPI];
    __shared__ int keep[NPI];
    __shared__ int cnt;

    float W1 = (float)(*wptr - 1);
    float H1 = (float)(*hptr - 1);

    if (threadIdx.x == 0) cnt = 0;
    for (int i = threadIdx.x; i < NPI; i += blockDim.x) key[i] = 0ULL;
    __syncthreads();

    for (int m = threadIdx.x; m < NPI; m += blockDim.x) {
        int g = img * NPI + m;
        float prob = expf(logits[(size_t)g * NCLS + cls] - rowmax[g]) / den[g];
        if (prob > SCORE_T) {
            float x1 = props[g * 4 + 0], y1 = props[g * 4 + 1];
            float x2 = props[g * 4 + 2], y2 = props[g * 4 + 3];
            float w  = x2 - x1 + 1.0f, h = y2 - y1 + 1.0f;
            float cx = x1 + 0.5f * w,  cy = y1 + 0.5f * h;
            const float* rc = boxreg + (size_t)g * (4 * NCLS) + 4 * cls;
            float dx = rc[0] / 10.0f, dy = rc[1] / 10.0f;
            float dw = fminf(rc[2] / 5.0f, BBOX_CLIP);
            float dh = fminf(rc[3] / 5.0f, BBOX_CLIP);
            float pcx = dx * w + cx, pcy = dy * h + cy;
            float pw = expf(dw) * w, ph = expf(dh) * h;
            float bx1 = pcx - 0.5f * pw;
            float by1 = pcy - 0.5f * ph;
            float bx2 = pcx + 0.5f * pw - 1.0f;
            float by2 = pcy + 0.5f * ph - 1.0f;
            bx1 = fminf(fmaxf(bx1, 0.f), W1);
            bx2 = fminf(fmaxf(bx2, 0.f), W1);
            by1 = fminf(fmaxf(by1, 0.f), H1);
            by2 = fminf(fmaxf(by2, 0.f), H1);
            box_lds[m][0] = bx1; box_lds[m][1] = by1;
            box_lds[m][2] = bx2; box_lds[m][3] = by2;
            int p = atomicAdd(&cnt, 1);
            unsigned fb = __float_as_uint(prob);
            key[p] = ((unsigned long long)fb << 32) | (unsigned)(NPI - 1 - m);
        }
    }
    __syncthreads();
    int n = cnt;

    // bitonic sort over next-pow2(n) slots only (rest are 0 sentinels anyway)
    int P = 2;
    while (P < n) P <<= 1;
    if (n > 1) {
        for (int k = 2; k <= P; k <<= 1) {
            for (int j = k >> 1; j > 0; j >>= 1) {
                for (int i = threadIdx.x; i < P; i += blockDim.x) {
                    int ixj = i ^ j;
                    if (ixj > i) {
                        unsigned long long a = key[i], b = key[ixj];
                        bool up = (i & k) == 0;
                        if (up ? (a < b) : (a > b)) { key[i] = b; key[ixj] = a; }
                    }
                }
                __syncthreads();
            }
        }
    }

    for (int i = threadIdx.x; i < NPI; i += blockDim.x) keep[i] = (i < n) ? 1 : 0;
    __syncthreads();

    // greedy NMS
    for (int i = 0; i < n; ++i) {
        if (keep[i]) {
            unsigned long long ki = key[i];
            int mi = NPI - 1 - (int)(ki & 0xFFFFFFFFu);
            float ax1 = box_lds[mi][0], ay1 = box_lds[mi][1];
            float ax2 = box_lds[mi][2], ay2 = box_lds[mi][3];
            float aarea = (ax2 - ax1 + 1.f) * (ay2 - ay1 + 1.f);
            for (int jj = i + 1 + (int)threadIdx.x; jj < n; jj += blockDim.x) {
                if (keep[jj]) {
                    int mj = NPI - 1 - (int)(key[jj] & 0xFFFFFFFFu);
                    float bx1 = box_lds[mj][0], by1 = box_lds[mj][1];
                    float bx2 = box_lds[mj][2], by2 = box_lds[mj][3];
                    float xx1 = fmaxf(ax1, bx1), yy1 = fmaxf(ay1, by1);
                    float xx2 = fminf(ax2, bx2), yy2 = fminf(ay2, by2);
                    float iw = fmaxf(xx2 - xx1 + 1.f, 0.f);
                    float ih = fmaxf(yy2 - yy1 + 1.f, 0.f);
                    float inter = iw * ih;
                    float barea = (bx2 - bx1 + 1.f) * (by2 - by1 + 1.f);
                    float iou = inter / (aarea + barea - inter);
                    if (iou > NMS_T) keep[jj] = 0;
                }
            }
        }
        __syncthreads();
    }

    // compact first <=100 kept entries; key sent to merge = c*1024 + rank-in-sorted
    if (threadIdx.x == 0) {
        int outn = 0;
        for (int i = 0; i < n && outn < DETS; ++i) {
            if (keep[i]) {
                unsigned long long ki = key[i];
                float sc = __uint_as_float((unsigned)(ki >> 32));
                int mi = NPI - 1 - (int)(ki & 0xFFFFFFFFu);
                int slot = pid * DETS + outn;
                out_score[slot] = sc;
                out_key[slot] = (unsigned)(c * NPI + i);
                out_box[slot * 4 + 0] = box_lds[mi][0];
                out_box[slot * 4 + 1] = box_lds[mi][1];
                out_box[slot * 4 + 2] = box_lds[mi][2];
                out_box[slot * 4 + 3] = box_lds[mi][3];
                ++outn;
            }
        }
        out_cnt[pid] = outn;
    }
}

// ---------------- Kernel 3: per-image top-100 merge ----------------
// 1 block / image, 1024 threads. Bitonic sort 8192 packed keys, then
// 100 threads emit outputs in parallel.
// key = score_bits<<32 | (0x1FFFF - flatkey)<<13 | p
//   flatkey = c*1024 + class-sorted-rank (17 bits, unique) -> tie-break
//   p = position in escore/ebox arrays (13 bits) -> box retrieval
__global__ __launch_bounds__(1024) void topk_merge(
    const int* __restrict__ cnts, const float* __restrict__ escore,
    const unsigned* __restrict__ ekey, const float* __restrict__ ebox,
    float* __restrict__ out)
{
    int img = blockIdx.x;
    __shared__ unsigned long long keys[MERGE_N];

    for (int p = threadIdx.x; p < MERGE_N; p += blockDim.x) {
        unsigned long long kv = 0ULL;
        if (p < NFG * DETS) {
            int cc = p / DETS, k = p % DETS;
            if (k < cnts[img * NFG + cc]) {
                int gp = img * NFG * DETS + p;
                unsigned fb = __float_as_uint(escore[gp]);
                unsigned low = ((0x1FFFFu - ekey[gp]) << 13) | (unsigned)p;
                kv = ((unsigned long long)fb << 32) | low;
            }
        }
        keys[p] = kv;
    }
    __syncthreads();

    // bitonic sort descending, 8192 elements
    for (int k = 2; k <= MERGE_N; k <<= 1) {
        for (int j = k >> 1; j > 0; j >>= 1) {
            for (int i = threadIdx.x; i < MERGE_N; i += blockDim.x) {
                int ixj = i ^ j;
                if (ixj > i) {
                    unsigned long long a = keys[i], b = keys[ixj];
                    bool up = (i & k) == 0;
                    if (up ? (a < b) : (a > b)) { keys[i] = b; keys[ixj] = a; }
                }
            }
            __syncthreads();
        }
    }

    float* oScore = out;                        // [8][100]
    float* oBox   = out + NIMG * DETS;          // [8][100][4]
    float* oLab   = out + NIMG * DETS * 5;      // [8][100]

    if (threadIdx.x < DETS) {
        int k = threadIdx.x;
        unsigned long long b = keys[k];
        int o = img * DETS + k;
        if (b != 0ULL) {
            float sc = __uint_as_float((unsigned)(b >> 32));
            unsigned low = (unsigned)(b & 0xFFFFFFFFu);
            unsigned flatkey = 0x1FFFFu - ((low >> 13) & 0x1FFFFu);
            int p = (int)(low & 0x1FFFu);
            int gp = img * NFG * DETS + p;
            oScore[o] = sc;
            oBox[o * 4 + 0] = ebox[gp * 4 + 0];
            oBox[o * 4 + 1] = ebox[gp * 4 + 1];
            oBox[o * 4 + 2] = ebox[gp * 4 + 2];
            oBox[o * 4 + 3] = ebox[gp * 4 + 3];
            oLab[o] = (float)((flatkey >> 10) + 1);
        } else {
            oScore[o] = 0.f;
            oBox[o * 4 + 0] = 0.f; oBox[o * 4 + 1] = 0.f;
            oBox[o * 4 + 2] = 0.f; oBox[o * 4 + 3] = 0.f;
            oLab[o] = 0.f;
        }
    }
}

extern "C" void kernel_launch(void* const* d_in, const int* in_sizes, int n_in,
                              void* d_out, int out_size, void* d_ws, size_t ws_size,
                              hipStream_t stream) {
    const float* logits = (const float*)d_in[0];
    const float* boxreg = (const float*)d_in[1];
    const float* props  = (const float*)d_in[2];
    const int*   hptr   = (const int*)d_in[3];
    const int*   wptr   = (const int*)d_in[4];
    float* out = (float*)d_out;
    int M = in_sizes[0] / NCLS; // 8192

    char* ws = (char*)d_ws;
    float*    rowmax = (float*)ws;    ws += (size_t)M * sizeof(float);
    float*    den    = (float*)ws;    ws += (size_t)M * sizeof(float);
    int*      cnt    = (int*)ws;      ws += (size_t)NIMG * NFG * sizeof(int);
    float*    escore = (float*)ws;    ws += (size_t)NIMG * NFG * DETS * sizeof(float);
    unsigned* ekey   = (unsigned*)ws; ws += (size_t)NIMG * NFG * DETS * sizeof(unsigned);
    float*    ebox   = (float*)ws;    ws += (size_t)NIMG * NFG * DETS * 4 * sizeof(float);

    softmax_stats<<<(M + 255) / 256, 256, 0, stream>>>(logits, rowmax, den, M);
    per_class_nms<<<NIMG * NFG, 256, 0, stream>>>(
        logits, boxreg, props, rowmax, den, hptr, wptr, cnt, escore, ekey, ebox);
    topk_merge<<<NIMG, 1024, 0, stream>>>(cnt, escore, ekey, ebox, out);
}

// Round 3
// 61.415 us; speedup vs baseline: 6.2276x; 3.0028x over previous
//
#include <hip/hip_runtime.h>
#include <stdint.h>
#include <math.h>

#define NCLS 81
#define NFG  80
#define NPI  1024
#define NIMG 8
#define DETS 100
#define SCORE_T 0.05f
#define NMS_T   0.5f
#define NCAND   (NFG * DETS)   // 8000
#define CAND_CAP 2048
#define FASTN 256              // mask-NMS fast-path limit

static constexpr float BBOX_CLIP = 4.1351665567423557f; // log(1000/16)

// ---------------- Kernel 1: per-row softmax stats ----------------
__global__ __launch_bounds__(256) void softmax_stats(
    const float* __restrict__ logits, float* __restrict__ rowmax,
    float* __restrict__ den, int M)
{
    int m = blockIdx.x * blockDim.x + threadIdx.x;
    if (m >= M) return;
    const float* r = logits + (size_t)m * NCLS;
    float mx = r[0];
    #pragma unroll
    for (int j = 1; j < NCLS; ++j) mx = fmaxf(mx, r[j]);
    float s = 0.f;
    #pragma unroll
    for (int j = 0; j < NCLS; ++j) s += expf(r[j] - mx);
    rowmax[m] = mx;
    den[m] = s;
}

// ---------------- Kernel 2: per-(image,class) NMS ----------------
__global__ __launch_bounds__(256) void per_class_nms(
    const float* __restrict__ logits, const float* __restrict__ boxreg,
    const float* __restrict__ props, const float* __restrict__ rowmax,
    const float* __restrict__ den, const int* __restrict__ hptr,
    const int* __restrict__ wptr, int* __restrict__ out_cnt,
    float* __restrict__ out_score, unsigned* __restrict__ out_key,
    float* __restrict__ out_box)
{
    int pid = blockIdx.x;           // 0..639
    int img = pid / NFG;
    int c   = pid % NFG;            // fg class row; label = c+1
    int cls = c + 1;

    __shared__ float box_lds[NPI][4];               // 16KB (by proposal id)
    __shared__ unsigned long long key[NPI];         // 8KB
    __shared__ int keep[NPI];                       // 4KB
    __shared__ float sbox[FASTN][4];                // 4KB (sorted order)
    __shared__ float sarea[FASTN];                  // 1KB
    __shared__ unsigned long long mask[FASTN][FASTN/64]; // 8KB
    __shared__ unsigned long long keepw[FASTN/64];
    __shared__ unsigned wpre[4];
    __shared__ int cnt;

    float W1 = (float)(*wptr - 1);
    float H1 = (float)(*hptr - 1);

    if (threadIdx.x == 0) cnt = 0;
    for (int i = threadIdx.x; i < NPI; i += blockDim.x) key[i] = 0ULL;
    __syncthreads();

    for (int m = threadIdx.x; m < NPI; m += blockDim.x) {
        int g = img * NPI + m;
        float prob = expf(logits[(size_t)g * NCLS + cls] - rowmax[g]) / den[g];
        if (prob > SCORE_T) {
            float x1 = props[g * 4 + 0], y1 = props[g * 4 + 1];
            float x2 = props[g * 4 + 2], y2 = props[g * 4 + 3];
            float w  = x2 - x1 + 1.0f, h = y2 - y1 + 1.0f;
            float cx = x1 + 0.5f * w,  cy = y1 + 0.5f * h;
            const float* rc = boxreg + (size_t)g * (4 * NCLS) + 4 * cls;
            float dx = rc[0] / 10.0f, dy = rc[1] / 10.0f;
            float dw = fminf(rc[2] / 5.0f, BBOX_CLIP);
            float dh = fminf(rc[3] / 5.0f, BBOX_CLIP);
            float pcx = dx * w + cx, pcy = dy * h + cy;
            float pw = expf(dw) * w, ph = expf(dh) * h;
            float bx1 = pcx - 0.5f * pw;
            float by1 = pcy - 0.5f * ph;
            float bx2 = pcx + 0.5f * pw - 1.0f;
            float by2 = pcy + 0.5f * ph - 1.0f;
            bx1 = fminf(fmaxf(bx1, 0.f), W1);
            bx2 = fminf(fmaxf(bx2, 0.f), W1);
            by1 = fminf(fmaxf(by1, 0.f), H1);
            by2 = fminf(fmaxf(by2, 0.f), H1);
            box_lds[m][0] = bx1; box_lds[m][1] = by1;
            box_lds[m][2] = bx2; box_lds[m][3] = by2;
            int p = atomicAdd(&cnt, 1);
            unsigned fb = __float_as_uint(prob);
            key[p] = ((unsigned long long)fb << 32) | (unsigned)(NPI - 1 - m);
        }
    }
    __syncthreads();
    int n = cnt;

    // bitonic sort over next-pow2(n) slots (rest are 0 sentinels)
    int P = 2;
    while (P < n) P <<= 1;
    if (n > 1) {
        for (int k = 2; k <= P; k <<= 1) {
            for (int j = k >> 1; j > 0; j >>= 1) {
                for (int i = threadIdx.x; i < P; i += blockDim.x) {
                    int ixj = i ^ j;
                    if (ixj > i) {
                        unsigned long long a = key[i], b = key[ixj];
                        bool up = (i & k) == 0;
                        if (up ? (a < b) : (a > b)) { key[i] = b; key[ixj] = a; }
                    }
                }
                __syncthreads();
            }
        }
    }

    for (int i = threadIdx.x; i < NPI; i += blockDim.x) keep[i] = 0;
    __syncthreads();

    if (n <= FASTN) {
        // ---------- fast path: bitmask NMS ----------
        for (int i = threadIdx.x; i < n; i += blockDim.x) {
            int mi = NPI - 1 - (int)(key[i] & 0xFFFFFFFFu);
            float bx1 = box_lds[mi][0], by1 = box_lds[mi][1];
            float bx2 = box_lds[mi][2], by2 = box_lds[mi][3];
            sbox[i][0] = bx1; sbox[i][1] = by1; sbox[i][2] = bx2; sbox[i][3] = by2;
            sarea[i] = (bx2 - bx1 + 1.f) * (by2 - by1 + 1.f);
        }
        __syncthreads();
        int nwords = ((n + 63) >> 6);
        for (int w = threadIdx.x; w < n * (FASTN/64); w += blockDim.x) {
            int i = w >> 2, wb = w & 3;
            if (wb >= nwords || ((wb + 1) << 6) - 1 <= i) { mask[i][wb] = 0ULL; continue; }
            float ax1 = sbox[i][0], ay1 = sbox[i][1];
            float ax2 = sbox[i][2], ay2 = sbox[i][3];
            float aarea = sarea[i];
            unsigned long long bits = 0ULL;
            int jbase = wb << 6;
            #pragma unroll 4
            for (int b = 0; b < 64; ++b) {
                int j = jbase + b;
                if (j < n && j > i) {
                    float bx1 = sbox[j][0], by1 = sbox[j][1];
                    float bx2 = sbox[j][2], by2 = sbox[j][3];
                    float xx1 = fmaxf(ax1, bx1), yy1 = fmaxf(ay1, by1);
                    float xx2 = fminf(ax2, bx2), yy2 = fminf(ay2, by2);
                    float iw = fmaxf(xx2 - xx1 + 1.f, 0.f);
                    float ih = fmaxf(yy2 - yy1 + 1.f, 0.f);
                    float inter = iw * ih;
                    float iou = inter / (aarea + sarea[j] - inter);
                    if (iou > NMS_T) bits |= (1ULL << b);
                }
            }
            mask[i][wb] = bits;
        }
        __syncthreads();
        if (threadIdx.x < 64) {
            int lane = threadIdx.x;
            unsigned long long kb = 0ULL;
            if (lane < 4) {
                int rem = n - (lane << 6);
                if (rem >= 64) kb = ~0ULL;
                else if (rem > 0) kb = (1ULL << rem) - 1ULL;
            }
            unsigned long long rm = 0ULL;
            for (int i = 0; i < n; ++i) {
                unsigned long long rw = __shfl(rm, i >> 6, 64);
                if (!((rw >> (i & 63)) & 1ULL)) {
                    unsigned long long mrow = (lane < 4) ? mask[i][lane] : 0ULL;
                    rm |= mrow;
                }
            }
            if (lane < 4) keepw[lane] = kb & ~rm;
        }
        __syncthreads();
        for (int i = threadIdx.x; i < n; i += blockDim.x)
            keep[i] = (int)((keepw[i >> 6] >> (i & 63)) & 1ULL);
        __syncthreads();
    } else {
        // ---------- slow path: serial greedy ----------
        for (int i = threadIdx.x; i < n; i += blockDim.x) keep[i] = 1;
        __syncthreads();
        for (int i = 0; i < n; ++i) {
            if (keep[i]) {
                unsigned long long ki = key[i];
                int mi = NPI - 1 - (int)(ki & 0xFFFFFFFFu);
                float ax1 = box_lds[mi][0], ay1 = box_lds[mi][1];
                float ax2 = box_lds[mi][2], ay2 = box_lds[mi][3];
                float aarea = (ax2 - ax1 + 1.f) * (ay2 - ay1 + 1.f);
                for (int jj = i + 1 + (int)threadIdx.x; jj < n; jj += blockDim.x) {
                    if (keep[jj]) {
                        int mj = NPI - 1 - (int)(key[jj] & 0xFFFFFFFFu);
                        float bx1 = box_lds[mj][0], by1 = box_lds[mj][1];
                        float bx2 = box_lds[mj][2], by2 = box_lds[mj][3];
                        float xx1 = fmaxf(ax1, bx1), yy1 = fmaxf(ay1, by1);
                        float xx2 = fminf(ax2, bx2), yy2 = fminf(ay2, by2);
                        float iw = fmaxf(xx2 - xx1 + 1.f, 0.f);
                        float ih = fmaxf(yy2 - yy1 + 1.f, 0.f);
                        float inter = iw * ih;
                        float barea = (bx2 - bx1 + 1.f) * (by2 - by1 + 1.f);
                        float iou = inter / (aarea + barea - inter);
                        if (iou > NMS_T) keep[jj] = 0;
                    }
                }
            }
            __syncthreads();
        }
    }

    // ---------- parallel compaction via block prefix scan ----------
    {
        int t = threadIdx.x, lane = t & 63, w = t >> 6;
        int k0 = keep[4 * t], k1 = keep[4 * t + 1];
        int k2 = keep[4 * t + 2], k3 = keep[4 * t + 3];
        unsigned s = (unsigned)(k0 + k1 + k2 + k3);
        unsigned v = s;
        #pragma unroll
        for (int off = 1; off < 64; off <<= 1) {
            unsigned u = __shfl_up(v, off, 64);
            v += (lane >= off) ? u : 0u;
        }
        if (lane == 63) wpre[w] = v;
        __syncthreads();
        unsigned woff = 0;
        for (int w2 = 0; w2 < w; ++w2) woff += wpre[w2];
        unsigned before = v + woff - s;
        unsigned r = before;
        #pragma unroll
        for (int j = 0; j < 4; ++j) {
            int i = 4 * t + j;
            int kv = (j == 0) ? k0 : (j == 1) ? k1 : (j == 2) ? k2 : k3;
            if (kv && r < DETS) {
                unsigned long long ki = key[i];
                int mi = NPI - 1 - (int)(ki & 0xFFFFFFFFu);
                int slot = pid * DETS + (int)r;
                out_score[slot] = __uint_as_float((unsigned)(ki >> 32));
                out_key[slot] = (unsigned)(c * NPI + i);
                out_box[slot * 4 + 0] = box_lds[mi][0];
                out_box[slot * 4 + 1] = box_lds[mi][1];
                out_box[slot * 4 + 2] = box_lds[mi][2];
                out_box[slot * 4 + 3] = box_lds[mi][3];
            }
            r += (unsigned)kv;
        }
        if (t == 0) {
            // total kept (after sync all wpre valid)
        }
        __syncthreads();
        if (t == 0) {
            unsigned tot = wpre[0] + wpre[1] + wpre[2] + wpre[3];
            out_cnt[pid] = (int)(tot < DETS ? tot : DETS);
        }
    }
}

// ---------------- Kernel 3: per-image top-100 via radix-select ----------------
// key = score_bits<<32 | (0x1FFFF - flatkey)<<13 | p
__device__ __forceinline__ void suffix_select(
    unsigned* hist, unsigned* wtot, int K, int* outB, unsigned* outAbove)
{
    int t = threadIdx.x, lane = t & 63, w = t >> 6;
    unsigned c0 = hist[4 * t], c1 = hist[4 * t + 1];
    unsigned c2 = hist[4 * t + 2], c3 = hist[4 * t + 3];
    unsigned ps = c0 + c1 + c2 + c3;
    unsigned v = ps;
    #pragma unroll
    for (int off = 1; off < 64; off <<= 1) {
        unsigned u = __shfl_down(v, off, 64);
        v += (lane + off < 64) ? u : 0u;
    }
    if (lane == 0) wtot[w] = v;
    __syncthreads();
    unsigned woff = 0;
    for (int w2 = w + 1; w2 < 16; ++w2) woff += wtot[w2];
    unsigned Sown = v + woff;          // suffix incl own 4 buckets
    unsigned A3 = Sown - ps;
    unsigned A2 = A3 + c3, A1 = A2 + c2, A0 = A1 + c1;
    unsigned A[4] = {A0, A1, A2, A3};
    unsigned C[4] = {c0, c1, c2, c3};
    #pragma unroll
    for (int j = 0; j < 4; ++j) {
        if ((int)A[j] < K && (int)(A[j] + C[j]) >= K) {
            *outB = 4 * t + j;
            *outAbove = A[j];
        }
    }
    __syncthreads();
}

__global__ __launch_bounds__(1024) void topk_merge(
    const int* __restrict__ cnts, const float* __restrict__ escore,
    const unsigned* __restrict__ ekey, const float* __restrict__ ebox,
    float* __restrict__ out)
{
    int img = blockIdx.x;
    __shared__ unsigned sc[NCAND];                  // 32000B
    __shared__ unsigned hist[4096];                 // 16KB
    __shared__ unsigned long long cand[CAND_CAP];   // 16KB
    __shared__ unsigned wtot[16];
    __shared__ int sB1, sB2, sNc;
    __shared__ unsigned sAb1, sAb2;

    int t = threadIdx.x;
    if (t == 0) { sB1 = 0; sB2 = 0; sNc = 0; sAb1 = 0; sAb2 = 0; }
    for (int p = t; p < NCAND; p += 1024) {
        int cc = p / DETS, k = p % DETS;
        unsigned fb = 0;
        if (k < cnts[img * NFG + cc]) fb = __float_as_uint(escore[img * NCAND + p]);
        sc[p] = fb;
    }
    for (int i = t; i < 4096; i += 1024) hist[i] = 0;
    __syncthreads();

    // L1 histogram on score bits [30:19]
    for (int p = t; p < NCAND; p += 1024) {
        unsigned fb = sc[p];
        if (fb) atomicAdd(&hist[fb >> 19], 1u);
    }
    __syncthreads();
    suffix_select(hist, wtot, DETS, &sB1, &sAb1);
    int B1 = sB1;
    unsigned ab1 = sAb1;

    // L2 histogram on bits [18:7], within bucket B1
    for (int i = t; i < 4096; i += 1024) hist[i] = 0;
    __syncthreads();
    for (int p = t; p < NCAND; p += 1024) {
        unsigned fb = sc[p];
        if (fb && (int)(fb >> 19) == B1) atomicAdd(&hist[(fb >> 7) & 0xFFFu], 1u);
    }
    __syncthreads();
    suffix_select(hist, wtot, DETS - (int)ab1, &sB2, &sAb2);
    int B2 = sB2;

    // compact candidates: prefix >= (B1,B2)
    for (int p = t; p < NCAND; p += 1024) {
        unsigned fb = sc[p];
        if (fb) {
            int d1 = (int)(fb >> 19);
            bool ok = d1 > B1 || (d1 == B1 && (int)((fb >> 7) & 0xFFFu) >= B2);
            if (ok) {
                int pos = atomicAdd(&sNc, 1);
                if (pos < CAND_CAP) {
                    unsigned fk = ekey[img * NCAND + p];
                    unsigned low = ((0x1FFFFu - fk) << 13) | (unsigned)p;
                    cand[pos] = ((unsigned long long)fb << 32) | low;
                }
            }
        }
    }
    __syncthreads();
    int nc = sNc < CAND_CAP ? sNc : CAND_CAP;
    int P = 128;
    while (P < nc) P <<= 1;
    for (int i = t; i < P; i += 1024)
        if (i >= nc) cand[i] = 0ULL;
    __syncthreads();

    // bitonic sort descending, P elements
    for (int k = 2; k <= P; k <<= 1) {
        for (int j = k >> 1; j > 0; j >>= 1) {
            for (int i = t; i < P; i += 1024) {
                int ixj = i ^ j;
                if (ixj > i) {
                    unsigned long long a = cand[i], b = cand[ixj];
                    bool up = (i & k) == 0;
                    if (up ? (a < b) : (a > b)) { cand[i] = b; cand[ixj] = a; }
                }
            }
            __syncthreads();
        }
    }

    float* oScore = out;                        // [8][100]
    float* oBox   = out + NIMG * DETS;          // [8][100][4]
    float* oLab   = out + NIMG * DETS * 5;      // [8][100]

    if (t < DETS) {
        unsigned long long b = cand[t];
        int o = img * DETS + t;
        if (b != 0ULL) {
            float scv = __uint_as_float((unsigned)(b >> 32));
            unsigned low = (unsigned)(b & 0xFFFFFFFFu);
            unsigned flatkey = 0x1FFFFu - ((low >> 13) & 0x1FFFFu);
            int p = (int)(low & 0x1FFFu);
            int gp = img * NCAND + p;
            oScore[o] = scv;
            oBox[o * 4 + 0] = ebox[gp * 4 + 0];
            oBox[o * 4 + 1] = ebox[gp * 4 + 1];
            oBox[o * 4 + 2] = ebox[gp * 4 + 2];
            oBox[o * 4 + 3] = ebox[gp * 4 + 3];
            oLab[o] = (float)((flatkey >> 10) + 1);
        } else {
            oScore[o] = 0.f;
            oBox[o * 4 + 0] = 0.f; oBox[o * 4 + 1] = 0.f;
            oBox[o * 4 + 2] = 0.f; oBox[o * 4 + 3] = 0.f;
            oLab[o] = 0.f;
        }
    }
}

extern "C" void kernel_launch(void* const* d_in, const int* in_sizes, int n_in,
                              void* d_out, int out_size, void* d_ws, size_t ws_size,
                              hipStream_t stream) {
    const float* logits = (const float*)d_in[0];
    const float* boxreg = (const float*)d_in[1];
    const float* props  = (const float*)d_in[2];
    const int*   hptr   = (const int*)d_in[3];
    const int*   wptr   = (const int*)d_in[4];
    float* out = (float*)d_out;
    int M = in_sizes[0] / NCLS; // 8192

    char* ws = (char*)d_ws;
    float*    rowmax = (float*)ws;    ws += (size_t)M * sizeof(float);
    float*    den    = (float*)ws;    ws += (size_t)M * sizeof(float);
    int*      cnt    = (int*)ws;      ws += (size_t)NIMG * NFG * sizeof(int);
    float*    escore = (float*)ws;    ws += (size_t)NIMG * NCAND * sizeof(float);
    unsigned* ekey   = (unsigned*)ws; ws += (size_t)NIMG * NCAND * sizeof(unsigned);
    float*    ebox   = (float*)ws;    ws += (size_t)NIMG * NCAND * 4 * sizeof(float);

    softmax_stats<<<(M + 255) / 256, 256, 0, stream>>>(logits, rowmax, den, M);
    per_class_nms<<<NIMG * NFG, 256, 0, stream>>>(
        logits, boxreg, props, rowmax, den, hptr, wptr, cnt, escore, ekey, ebox);
    topk_merge<<<NIMG, 1024, 0, stream>>>(cnt, escore, ekey, ebox, out);
}

// Round 5
// 60.857 us; speedup vs baseline: 6.2847x; 1.0092x over previous
//
#include <hip/hip_runtime.h>
#include <stdint.h>
#include <math.h>

#define NCLS 81
#define NFG  80
#define NPI  1024
#define NIMG 8
#define DETS 100
#define SCORE_T 0.05f
#define NMS_T   0.5f
#define NCAND   (NFG * DETS)   // 8000
#define CAND_CAP 2048
#define FASTN 256              // block bitmask-NMS path limit
#define ROWS 64                // rows per softmax block

static constexpr float BBOX_CLIP = 4.1351665567423557f; // log(1000/16)

// ---------------- Kernel 1: softmax -> transposed prob matrix ----------------
// probT[c][row], c = fg class index 0..79 (class c+1), row = 0..M-1.
// Serial per-row max/den in original element order (bit-exact vs prior rounds).
__global__ __launch_bounds__(256) void softmax_probT(
    const float* __restrict__ logits, float* __restrict__ probT, int M)
{
    __shared__ float tile[ROWS * NCLS];   // 20736 B
    __shared__ float mx[ROWS], dn[ROWS];
    int t = threadIdx.x;
    int rbase = blockIdx.x * ROWS;

    for (int idx = t; idx < ROWS * NCLS; idx += 256)
        tile[idx] = logits[(size_t)rbase * NCLS + idx];
    __syncthreads();

    if (t < ROWS) {
        const float* r = tile + t * NCLS;
        float m = r[0];
        #pragma unroll
        for (int j = 1; j < NCLS; ++j) m = fmaxf(m, r[j]);
        float s = 0.f;
        #pragma unroll
        for (int j = 0; j < NCLS; ++j) s += expf(r[j] - m);
        mx[t] = m; dn[t] = s;
    }
    __syncthreads();

    for (int o = t; o < ROWS * NFG; o += 256) {
        int r = o & 63;
        int c = o >> 6;                         // 0..79
        float v = expf(tile[r * NCLS + (c + 1)] - mx[r]) / dn[r];
        probT[(size_t)c * M + rbase + r] = v;   // coalesced 256B segments
    }
}

// ---------------- Kernel 2: per-(image,class) NMS ----------------
__global__ __launch_bounds__(256) void per_class_nms(
    const float* __restrict__ probT, const float* __restrict__ boxreg,
    const float* __restrict__ props, const int* __restrict__ hptr,
    const int* __restrict__ wptr, int* __restrict__ out_cnt,
    float* __restrict__ out_score, unsigned* __restrict__ out_key,
    float* __restrict__ out_box, int M)
{
    int pid = blockIdx.x;           // 0..639
    int img = pid / NFG;
    int c   = pid % NFG;            // fg class row; label = c+1
    int cls = c + 1;

    __shared__ float box_lds[NPI][4];               // 16KB (by proposal id)
    __shared__ unsigned long long key[NPI];         // 8KB
    __shared__ int keep[NPI];                       // 4KB
    __shared__ float sbox[FASTN][4];                // 4KB (sorted order)
    __shared__ float sarea[FASTN];                  // 1KB
    __shared__ unsigned long long mask[FASTN][FASTN/64]; // 8KB
    __shared__ unsigned long long keepw[FASTN/64];
    __shared__ unsigned wpre[4];
    __shared__ int cnt;

    int t = threadIdx.x;
    float W1 = (float)(*wptr - 1);
    float H1 = (float)(*hptr - 1);

    if (t == 0) cnt = 0;
    for (int i = t; i < NPI; i += 256) key[i] = 0ULL;
    __syncthreads();

    // ---- load phase: coalesced float4 prob read, decode passing proposals ----
    {
        const float4 pv = *(const float4*)(probT + (size_t)c * M + img * NPI + 4 * t);
        float pr[4] = {pv.x, pv.y, pv.z, pv.w};
        #pragma unroll
        for (int j = 0; j < 4; ++j) {
            if (pr[j] > SCORE_T) {
                int m = 4 * t + j;
                int g = img * NPI + m;
                const float4 pb = *(const float4*)(props + (size_t)g * 4);
                float x1 = pb.x, y1 = pb.y, x2 = pb.z, y2 = pb.w;
                float w  = x2 - x1 + 1.0f, h = y2 - y1 + 1.0f;
                float cx = x1 + 0.5f * w,  cy = y1 + 0.5f * h;
                const float4 rc = *(const float4*)(boxreg + (size_t)g * (4 * NCLS) + 4 * cls);
                float dx = rc.x / 10.0f, dy = rc.y / 10.0f;
                float dw = fminf(rc.z / 5.0f, BBOX_CLIP);
                float dh = fminf(rc.w / 5.0f, BBOX_CLIP);
                float pcx = dx * w + cx, pcy = dy * h + cy;
                float pw = expf(dw) * w, ph = expf(dh) * h;
                float bx1 = pcx - 0.5f * pw;
                float by1 = pcy - 0.5f * ph;
                float bx2 = pcx + 0.5f * pw - 1.0f;
                float by2 = pcy + 0.5f * ph - 1.0f;
                bx1 = fminf(fmaxf(bx1, 0.f), W1);
                bx2 = fminf(fmaxf(bx2, 0.f), W1);
                by1 = fminf(fmaxf(by1, 0.f), H1);
                by2 = fminf(fmaxf(by2, 0.f), H1);
                box_lds[m][0] = bx1; box_lds[m][1] = by1;
                box_lds[m][2] = bx2; box_lds[m][3] = by2;
                int p = atomicAdd(&cnt, 1);
                unsigned fb = __float_as_uint(pr[j]);
                key[p] = ((unsigned long long)fb << 32) | (unsigned)(NPI - 1 - m);
            }
        }
    }
    __syncthreads();
    int n = cnt;

    // ================= wave fast path: n <= 64, zero further syncs =================
    if (n <= 64) {
        if (t < 64) {
            int lane = t;
            unsigned long long k = (lane < n) ? key[lane] : 0ULL;
            // bitonic sort descending across 64 lanes (keys unique or 0)
            #pragma unroll
            for (int kk = 2; kk <= 64; kk <<= 1) {
                #pragma unroll
                for (int j = kk >> 1; j > 0; j >>= 1) {
                    unsigned long long o = __shfl_xor(k, j, 64);
                    bool up = ((lane & kk) == 0);
                    bool lower = ((lane & j) == 0);
                    bool take_max = (up == lower);
                    k = take_max ? (k > o ? k : o) : (k < o ? k : o);
                }
            }
            bool valid = (lane < n);
            float bx1 = 0.f, by1 = 0.f, bx2 = 0.f, by2 = 0.f, area = 0.f;
            if (valid) {
                int mi = NPI - 1 - (int)(k & 0xFFFFFFFFu);
                bx1 = box_lds[mi][0]; by1 = box_lds[mi][1];
                bx2 = box_lds[mi][2]; by2 = box_lds[mi][3];
                area = (bx2 - bx1 + 1.f) * (by2 - by1 + 1.f);
            }
            unsigned long long sup = 0ULL;
            for (int i = 0; i < n; ++i) {
                bool alive = !((sup >> i) & 1ULL);
                float ax1 = __shfl(bx1, i, 64), ay1 = __shfl(by1, i, 64);
                float ax2 = __shfl(bx2, i, 64), ay2 = __shfl(by2, i, 64);
                float aarea = __shfl(area, i, 64);
                bool s = false;
                if (alive && valid && lane > i) {
                    float xx1 = fmaxf(ax1, bx1), yy1 = fmaxf(ay1, by1);
                    float xx2 = fminf(ax2, bx2), yy2 = fminf(ay2, by2);
                    float iw = fmaxf(xx2 - xx1 + 1.f, 0.f);
                    float ih = fmaxf(yy2 - yy1 + 1.f, 0.f);
                    float inter = iw * ih;
                    float iou = inter / (aarea + area - inter);
                    s = iou > NMS_T;
                }
                sup |= __ballot(s);
            }
            bool kept = valid && !((sup >> lane) & 1ULL);
            unsigned long long keptm = __ballot(kept);
            int rank = __popcll(keptm & ((1ULL << lane) - 1ULL));
            if (kept && rank < DETS) {
                int slot = pid * DETS + rank;
                out_score[slot] = __uint_as_float((unsigned)(k >> 32));
                out_key[slot] = (unsigned)(c * NPI + lane);
                out_box[slot * 4 + 0] = bx1;
                out_box[slot * 4 + 1] = by1;
                out_box[slot * 4 + 2] = bx2;
                out_box[slot * 4 + 3] = by2;
            }
            if (lane == 0) {
                int tot = __popcll(keptm);
                out_cnt[pid] = tot < DETS ? tot : DETS;
            }
        }
        return;
    }

    // ================= block paths: n > 64 =================
    // bitonic sort over next-pow2(n) slots (rest are 0 sentinels)
    int P = 2;
    while (P < n) P <<= 1;
    for (int k = 2; k <= P; k <<= 1) {
        for (int j = k >> 1; j > 0; j >>= 1) {
            for (int i = t; i < P; i += 256) {
                int ixj = i ^ j;
                if (ixj > i) {
                    unsigned long long a = key[i], b = key[ixj];
                    bool up = (i & k) == 0;
                    if (up ? (a < b) : (a > b)) { key[i] = b; key[ixj] = a; }
                }
            }
            __syncthreads();
        }
    }

    for (int i = t; i < NPI; i += 256) keep[i] = 0;
    __syncthreads();

    if (n <= FASTN) {
        // ---------- bitmask NMS ----------
        for (int i = t; i < n; i += 256) {
            int mi = NPI - 1 - (int)(key[i] & 0xFFFFFFFFu);
            float bx1 = box_lds[mi][0], by1 = box_lds[mi][1];
            float bx2 = box_lds[mi][2], by2 = box_lds[mi][3];
            sbox[i][0] = bx1; sbox[i][1] = by1; sbox[i][2] = bx2; sbox[i][3] = by2;
            sarea[i] = (bx2 - bx1 + 1.f) * (by2 - by1 + 1.f);
        }
        __syncthreads();
        int nwords = ((n + 63) >> 6);
        for (int w = t; w < n * (FASTN/64); w += 256) {
            int i = w >> 2, wb = w & 3;
            if (wb >= nwords || ((wb + 1) << 6) - 1 <= i) { mask[i][wb] = 0ULL; continue; }
            float ax1 = sbox[i][0], ay1 = sbox[i][1];
            float ax2 = sbox[i][2], ay2 = sbox[i][3];
            float aarea = sarea[i];
            unsigned long long bits = 0ULL;
            int jbase = wb << 6;
            #pragma unroll 4
            for (int b = 0; b < 64; ++b) {
                int j = jbase + b;
                if (j < n && j > i) {
                    float bx1 = sbox[j][0], by1 = sbox[j][1];
                    float bx2 = sbox[j][2], by2 = sbox[j][3];
                    float xx1 = fmaxf(ax1, bx1), yy1 = fmaxf(ay1, by1);
                    float xx2 = fminf(ax2, bx2), yy2 = fminf(ay2, by2);
                    float iw = fmaxf(xx2 - xx1 + 1.f, 0.f);
                    float ih = fmaxf(yy2 - yy1 + 1.f, 0.f);
                    float inter = iw * ih;
                    float iou = inter / (aarea + sarea[j] - inter);
                    if (iou > NMS_T) bits |= (1ULL << b);
                }
            }
            mask[i][wb] = bits;
        }
        __syncthreads();
        if (t < 64) {
            int lane = t;
            unsigned long long kb = 0ULL;
            if (lane < 4) {
                int rem = n - (lane << 6);
                if (rem >= 64) kb = ~0ULL;
                else if (rem > 0) kb = (1ULL << rem) - 1ULL;
            }
            unsigned long long rm = 0ULL;
            for (int i = 0; i < n; ++i) {
                unsigned long long rw = __shfl(rm, i >> 6, 64);
                if (!((rw >> (i & 63)) & 1ULL)) {
                    unsigned long long mrow = (lane < 4) ? mask[i][lane] : 0ULL;
                    rm |= mrow;
                }
            }
            if (lane < 4) keepw[lane] = kb & ~rm;
        }
        __syncthreads();
        for (int i = t; i < n; i += 256)
            keep[i] = (int)((keepw[i >> 6] >> (i & 63)) & 1ULL);
        __syncthreads();
    } else {
        // ---------- serial greedy ----------
        for (int i = t; i < n; i += 256) keep[i] = 1;
        __syncthreads();
        for (int i = 0; i < n; ++i) {
            if (keep[i]) {
                unsigned long long ki = key[i];
                int mi = NPI - 1 - (int)(ki & 0xFFFFFFFFu);
                float ax1 = box_lds[mi][0], ay1 = box_lds[mi][1];
                float ax2 = box_lds[mi][2], ay2 = box_lds[mi][3];
                float aarea = (ax2 - ax1 + 1.f) * (ay2 - ay1 + 1.f);
                for (int jj = i + 1 + t; jj < n; jj += 256) {
                    if (keep[jj]) {
                        int mj = NPI - 1 - (int)(key[jj] & 0xFFFFFFFFu);
                        float bx1 = box_lds[mj][0], by1 = box_lds[mj][1];
                        float bx2 = box_lds[mj][2], by2 = box_lds[mj][3];
                        float xx1 = fmaxf(ax1, bx1), yy1 = fmaxf(ay1, by1);
                        float xx2 = fminf(ax2, bx2), yy2 = fminf(ay2, by2);
                        float iw = fmaxf(xx2 - xx1 + 1.f, 0.f);
                        float ih = fmaxf(yy2 - yy1 + 1.f, 0.f);
                        float inter = iw * ih;
                        float barea = (bx2 - bx1 + 1.f) * (by2 - by1 + 1.f);
                        float iou = inter / (aarea + barea - inter);
                        if (iou > NMS_T) keep[jj] = 0;
                    }
                }
            }
            __syncthreads();
        }
    }

    // ---------- parallel compaction via block prefix scan ----------
    {
        int lane = t & 63, w = t >> 6;
        int k0 = keep[4 * t], k1 = keep[4 * t + 1];
        int k2 = keep[4 * t + 2], k3 = keep[4 * t + 3];
        unsigned s = (unsigned)(k0 + k1 + k2 + k3);
        unsigned v = s;
        #pragma unroll
        for (int off = 1; off < 64; off <<= 1) {
            unsigned u = __shfl_up(v, off, 64);
            v += (lane >= off) ? u : 0u;
        }
        if (lane == 63) wpre[w] = v;
        __syncthreads();
        unsigned woff = 0;
        for (int w2 = 0; w2 < w; ++w2) woff += wpre[w2];
        unsigned before = v + woff - s;
        unsigned r = before;
        #pragma unroll
        for (int j = 0; j < 4; ++j) {
            int i = 4 * t + j;
            int kv = (j == 0) ? k0 : (j == 1) ? k1 : (j == 2) ? k2 : k3;
            if (kv && r < DETS) {
                unsigned long long ki = key[i];
                int mi = NPI - 1 - (int)(ki & 0xFFFFFFFFu);
                int slot = pid * DETS + (int)r;
                out_score[slot] = __uint_as_float((unsigned)(ki >> 32));
                out_key[slot] = (unsigned)(c * NPI + i);
                out_box[slot * 4 + 0] = box_lds[mi][0];
                out_box[slot * 4 + 1] = box_lds[mi][1];
                out_box[slot * 4 + 2] = box_lds[mi][2];
                out_box[slot * 4 + 3] = box_lds[mi][3];
            }
            r += (unsigned)kv;
        }
        __syncthreads();
        if (t == 0) {
            unsigned tot = wpre[0] + wpre[1] + wpre[2] + wpre[3];
            out_cnt[pid] = (int)(tot < DETS ? tot : DETS);
        }
    }
}

// ---------------- Kernel 3: per-image top-100 via radix-select ----------------
__device__ __forceinline__ void suffix_select(
    unsigned* hist, unsigned* wtot, int K, int* outB, unsigned* outAbove)
{
    int t = threadIdx.x, lane = t & 63, w = t >> 6;
    unsigned c0 = hist[4 * t], c1 = hist[4 * t + 1];
    unsigned c2 = hist[4 * t + 2], c3 = hist[4 * t + 3];
    unsigned ps = c0 + c1 + c2 + c3;
    unsigned v = ps;
    #pragma unroll
    for (int off = 1; off < 64; off <<= 1) {
        unsigned u = __shfl_down(v, off, 64);
        v += (lane + off < 64) ? u : 0u;
    }
    if (lane == 0) wtot[w] = v;
    __syncthreads();
    unsigned woff = 0;
    for (int w2 = w + 1; w2 < 16; ++w2) woff += wtot[w2];
    unsigned Sown = v + woff;
    unsigned A3 = Sown - ps;
    unsigned A2 = A3 + c3, A1 = A2 + c2, A0 = A1 + c1;
    unsigned A[4] = {A0, A1, A2, A3};
    unsigned C[4] = {c0, c1, c2, c3};
    #pragma unroll
    for (int j = 0; j < 4; ++j) {
        if ((int)A[j] < K && (int)(A[j] + C[j]) >= K) {
            *outB = 4 * t + j;
            *outAbove = A[j];
        }
    }
    __syncthreads();
}

__global__ __launch_bounds__(1024) void topk_merge(
    const int* __restrict__ cnts, const float* __restrict__ escore,
    const unsigned* __restrict__ ekey, const float* __restrict__ ebox,
    float* __restrict__ out)
{
    int img = blockIdx.x;
    __shared__ unsigned sc[NCAND];
    __shared__ unsigned hist[4096];
    __shared__ unsigned long long cand[CAND_CAP];
    __shared__ unsigned wtot[16];
    __shared__ int sB1, sB2, sNc;
    __shared__ unsigned sAb1, sAb2;

    int t = threadIdx.x;
    if (t == 0) { sB1 = 0; sB2 = 0; sNc = 0; sAb1 = 0; sAb2 = 0; }
    for (int p = t; p < NCAND; p += 1024) {
        int cc = p / DETS, k = p % DETS;
        unsigned fb = 0;
        if (k < cnts[img * NFG + cc]) fb = __float_as_uint(escore[img * NCAND + p]);
        sc[p] = fb;
    }
    for (int i = t; i < 4096; i += 1024) hist[i] = 0;
    __syncthreads();

    for (int p = t; p < NCAND; p += 1024) {
        unsigned fb = sc[p];
        if (fb) atomicAdd(&hist[fb >> 19], 1u);
    }
    __syncthreads();
    suffix_select(hist, wtot, DETS, &sB1, &sAb1);
    int B1 = sB1;
    unsigned ab1 = sAb1;

    for (int i = t; i < 4096; i += 1024) hist[i] = 0;
    __syncthreads();
    for (int p = t; p < NCAND; p += 1024) {
        unsigned fb = sc[p];
        if (fb && (int)(fb >> 19) == B1) atomicAdd(&hist[(fb >> 7) & 0xFFFu], 1u);
    }
    __syncthreads();
    suffix_select(hist, wtot, DETS - (int)ab1, &sB2, &sAb2);
    int B2 = sB2;

    for (int p = t; p < NCAND; p += 1024) {
        unsigned fb = sc[p];
        if (fb) {
            int d1 = (int)(fb >> 19);
            bool ok = d1 > B1 || (d1 == B1 && (int)((fb >> 7) & 0xFFFu) >= B2);
            if (ok) {
                int pos = atomicAdd(&sNc, 1);
                if (pos < CAND_CAP) {
                    unsigned fk = ekey[img * NCAND + p];
                    unsigned low = ((0x1FFFFu - fk) << 13) | (unsigned)p;
                    cand[pos] = ((unsigned long long)fb << 32) | low;
                }
            }
        }
    }
    __syncthreads();
    int nc = sNc < CAND_CAP ? sNc : CAND_CAP;
    int P = 128;
    while (P < nc) P <<= 1;
    for (int i = t; i < P; i += 1024)
        if (i >= nc) cand[i] = 0ULL;
    __syncthreads();

    for (int k = 2; k <= P; k <<= 1) {
        for (int j = k >> 1; j > 0; j >>= 1) {
            for (int i = t; i < P; i += 1024) {
                int ixj = i ^ j;
                if (ixj > i) {
                    unsigned long long a = cand[i], b = cand[ixj];
                    bool up = (i & k) == 0;
                    if (up ? (a < b) : (a > b)) { cand[i] = b; cand[ixj] = a; }
                }
            }
            __syncthreads();
        }
    }

    float* oScore = out;
    float* oBox   = out + NIMG * DETS;
    float* oLab   = out + NIMG * DETS * 5;

    if (t < DETS) {
        unsigned long long b = cand[t];
        int o = img * DETS + t;
        if (b != 0ULL) {
            float scv = __uint_as_float((unsigned)(b >> 32));
            unsigned low = (unsigned)(b & 0xFFFFFFFFu);
            unsigned flatkey = 0x1FFFFu - ((low >> 13) & 0x1FFFFu);
            int p = (int)(low & 0x1FFFu);
            int gp = img * NCAND + p;
            oScore[o] = scv;
            oBox[o * 4 + 0] = ebox[gp * 4 + 0];
            oBox[o * 4 + 1] = ebox[gp * 4 + 1];
            oBox[o * 4 + 2] = ebox[gp * 4 + 2];
            oBox[o * 4 + 3] = ebox[gp * 4 + 3];
            oLab[o] = (float)((flatkey >> 10) + 1);
        } else {
            oScore[o] = 0.f;
            oBox[o * 4 + 0] = 0.f; oBox[o * 4 + 1] = 0.f;
            oBox[o * 4 + 2] = 0.f; oBox[o * 4 + 3] = 0.f;
            oLab[o] = 0.f;
        }
    }
}

extern "C" void kernel_launch(void* const* d_in, const int* in_sizes, int n_in,
                              void* d_out, int out_size, void* d_ws, size_t ws_size,
                              hipStream_t stream) {
    const float* logits = (const float*)d_in[0];
    const float* boxreg = (const float*)d_in[1];
    const float* props  = (const float*)d_in[2];
    const int*   hptr   = (const int*)d_in[3];
    const int*   wptr   = (const int*)d_in[4];
    float* out = (float*)d_out;
    int M = in_sizes[0] / NCLS; // 8192

    char* ws = (char*)d_ws;
    float*    probT  = (float*)ws;    ws += (size_t)NFG * M * sizeof(float);
    int*      cnt    = (int*)ws;      ws += (size_t)NIMG * NFG * sizeof(int);
    float*    escore = (float*)ws;    ws += (size_t)NIMG * NCAND * sizeof(float);
    unsigned* ekey   = (unsigned*)ws; ws += (size_t)NIMG * NCAND * sizeof(unsigned);
    float*    ebox   = (float*)ws;    ws += (size_t)NIMG * NCAND * 4 * sizeof(float);

    softmax_probT<<<M / ROWS, 256, 0, stream>>>(logits, probT, M);
    per_class_nms<<<NIMG * NFG, 256, 0, stream>>>(
        probT, boxreg, props, hptr, wptr, cnt, escore, ekey, ebox, M);
    topk_merge<<<NIMG, 1024, 0, stream>>>(cnt, escore, ekey, ebox, out);
}